// Round 3
// baseline (1136.887 us; speedup 1.0000x reference)
//
#include <hip/hip_runtime.h>
#include <cstdint>

// ---------- types / helpers ----------
typedef __attribute__((ext_vector_type(8))) short bfrag;   // 8 bf16 in 4 VGPRs
typedef __attribute__((ext_vector_type(4))) float f4;

typedef __attribute__((address_space(1))) const void* gas_t;
typedef __attribute__((address_space(3))) void* las_t;

__device__ __forceinline__ void gload16(const void* g, void* l) {
  __builtin_amdgcn_global_load_lds((gas_t)g, (las_t)l, 16, 0, 0);
}

__device__ __forceinline__ unsigned short f2bf(float f) {
  union { float f; unsigned u; } v; v.f = f;
  unsigned r = v.u + 0x7fffu + ((v.u >> 16) & 1u);
  return (unsigned short)(r >> 16);
}
__device__ __forceinline__ float bf2f(unsigned short b) {
  union { unsigned u; float f; } v; v.u = ((unsigned)b) << 16;
  return v.f;
}
__device__ __forceinline__ unsigned cvt_pk_bf16(float lo, float hi) {
  unsigned r;
  asm("v_cvt_pk_bf16_f32 %0, %1, %2" : "=v"(r) : "v"(lo), "v"(hi));
  return r;
}

// ---------- transpose+convert: in[R][C] fp32 -> out[C][R] bf16 ----------
__global__ __launch_bounds__(256) void tconv_k(const float* __restrict__ in,
                                               unsigned short* __restrict__ out,
                                               int R, int C) {
  __shared__ unsigned short t[32][33];
  const int c0 = blockIdx.x * 32, r0 = blockIdx.y * 32;
  const int tid = threadIdx.x;
#pragma unroll
  for (int p = 0; p < 4; p++) {
    int flat = p * 256 + tid;
    int r = flat >> 5, c = flat & 31;
    t[r][c] = f2bf(in[(size_t)(r0 + r) * C + c0 + c]);
  }
  __syncthreads();
#pragma unroll
  for (int p = 0; p < 4; p++) {
    int flat = p * 256 + tid;
    int cc = flat >> 5, rr = flat & 31;
    out[(size_t)(c0 + cc) * R + r0 + rr] = t[rr][cc];
  }
}

// ---------- RMSNorm: x fp32 [rows][1024] -> bf16 ----------
__global__ __launch_bounds__(256) void rmsnorm_k(const float* __restrict__ x,
                                                 const float* __restrict__ g,
                                                 unsigned short* __restrict__ out) {
  const int row = blockIdx.x, tid = threadIdx.x;
  const float4 v = ((const float4*)(x + (size_t)row * 1024))[tid];
  float ss = v.x * v.x + v.y * v.y + v.z * v.z + v.w * v.w;
#pragma unroll
  for (int off = 1; off < 64; off <<= 1) ss += __shfl_xor(ss, off);
  __shared__ float red[4];
  if ((tid & 63) == 0) red[tid >> 6] = ss;
  __syncthreads();
  float tot = red[0] + red[1] + red[2] + red[3];
  float sc = rsqrtf(tot * (1.0f / 1024.0f) + 1e-6f);
  const float4 gv = ((const float4*)g)[tid];
  ushort4 o;
  o.x = f2bf(v.x * sc * gv.x);
  o.y = f2bf(v.y * sc * gv.y);
  o.z = f2bf(v.z * sc * gv.z);
  o.w = f2bf(v.w * sc * gv.w);
  ((ushort4*)out)[(size_t)row * 256 + tid] = o;
}

// ---------- GEMM: C[M,N] = A[M,K](bf16) @ Bt[N,K](bf16)^T ----------
// MODE 0: write bf16 C.  MODE 1: write fp32 C = acc + resid.
template <int MODE>
__global__ __launch_bounds__(256) void gemm_k(const unsigned short* __restrict__ A,
                                              const unsigned short* __restrict__ Bt,
                                              int M, int N, int K,
                                              void* __restrict__ Cout,
                                              const float* __restrict__ resid) {
  __shared__ unsigned short As[128 * 32];
  __shared__ unsigned short Bs[128 * 32];
  const int tid = threadIdx.x;
  const int wid = tid >> 6, lane = tid & 63;
  const int l15 = lane & 15, l4 = lane >> 4;
  const int brow = blockIdx.x * 128, bcol = blockIdx.y * 128;
  const int wr = (wid >> 1) * 64, wc = (wid & 1) * 64;
  f4 acc[4][4];
#pragma unroll
  for (int m = 0; m < 4; m++)
#pragma unroll
    for (int n = 0; n < 4; n++) acc[m][n] = (f4){0.f, 0.f, 0.f, 0.f};

  for (int k0 = 0; k0 < K; k0 += 32) {
#pragma unroll
    for (int c = 0; c < 2; c++) {
      int base = c * 256 + wid * 64;
      int e = base + lane;
      int row = e >> 2, col = (e & 3) * 8;
      gload16(A + (size_t)(brow + row) * K + k0 + col, &As[base * 8]);
      gload16(Bt + (size_t)(bcol + row) * K + k0 + col, &Bs[base * 8]);
    }
    __syncthreads();
    bfrag a[4], b[4];
#pragma unroll
    for (int m = 0; m < 4; m++) a[m] = *(const bfrag*)&As[(wr + m * 16 + l15) * 32 + l4 * 8];
#pragma unroll
    for (int n = 0; n < 4; n++) b[n] = *(const bfrag*)&Bs[(wc + n * 16 + l15) * 32 + l4 * 8];
#pragma unroll
    for (int m = 0; m < 4; m++)
#pragma unroll
      for (int n = 0; n < 4; n++)
        acc[m][n] = __builtin_amdgcn_mfma_f32_16x16x32_bf16(a[m], b[n], acc[m][n], 0, 0, 0);
    __syncthreads();
  }
#pragma unroll
  for (int m = 0; m < 4; m++)
#pragma unroll
    for (int n = 0; n < 4; n++)
#pragma unroll
      for (int j = 0; j < 4; j++) {
        int r = brow + wr + m * 16 + l4 * 4 + j;
        int col = bcol + wc + n * 16 + l15;
        if (MODE == 0) {
          ((unsigned short*)Cout)[(size_t)r * N + col] = f2bf(acc[m][n][j]);
        } else {
          ((float*)Cout)[(size_t)r * N + col] = acc[m][n][j] + resid[(size_t)r * N + col];
        }
      }
}

// ---------- fused FFN1: G = silu(A@W1t^T) * (A@W2t^T), bf16 out ----------
__global__ __launch_bounds__(256) void ffn1_k(const unsigned short* __restrict__ A,
                                              const unsigned short* __restrict__ B1t,
                                              const unsigned short* __restrict__ B2t,
                                              unsigned short* __restrict__ G,
                                              int M, int N, int K) {
  __shared__ unsigned short As[128 * 32];
  __shared__ unsigned short B1s[128 * 32];
  __shared__ unsigned short B2s[128 * 32];
  const int tid = threadIdx.x;
  const int wid = tid >> 6, lane = tid & 63;
  const int l15 = lane & 15, l4 = lane >> 4;
  const int brow = blockIdx.x * 128, bcol = blockIdx.y * 128;
  const int wr = (wid >> 1) * 64, wc = (wid & 1) * 64;
  f4 acc1[4][4], acc2[4][4];
#pragma unroll
  for (int m = 0; m < 4; m++)
#pragma unroll
    for (int n = 0; n < 4; n++) {
      acc1[m][n] = (f4){0.f, 0.f, 0.f, 0.f};
      acc2[m][n] = (f4){0.f, 0.f, 0.f, 0.f};
    }

  for (int k0 = 0; k0 < K; k0 += 32) {
#pragma unroll
    for (int c = 0; c < 2; c++) {
      int base = c * 256 + wid * 64;
      int e = base + lane;
      int row = e >> 2, col = (e & 3) * 8;
      gload16(A + (size_t)(brow + row) * K + k0 + col, &As[base * 8]);
      gload16(B1t + (size_t)(bcol + row) * K + k0 + col, &B1s[base * 8]);
      gload16(B2t + (size_t)(bcol + row) * K + k0 + col, &B2s[base * 8]);
    }
    __syncthreads();
    bfrag a[4], b1[4], b2[4];
#pragma unroll
    for (int m = 0; m < 4; m++) a[m] = *(const bfrag*)&As[(wr + m * 16 + l15) * 32 + l4 * 8];
#pragma unroll
    for (int n = 0; n < 4; n++) {
      b1[n] = *(const bfrag*)&B1s[(wc + n * 16 + l15) * 32 + l4 * 8];
      b2[n] = *(const bfrag*)&B2s[(wc + n * 16 + l15) * 32 + l4 * 8];
    }
#pragma unroll
    for (int m = 0; m < 4; m++)
#pragma unroll
      for (int n = 0; n < 4; n++) {
        acc1[m][n] = __builtin_amdgcn_mfma_f32_16x16x32_bf16(a[m], b1[n], acc1[m][n], 0, 0, 0);
        acc2[m][n] = __builtin_amdgcn_mfma_f32_16x16x32_bf16(a[m], b2[n], acc2[m][n], 0, 0, 0);
      }
    __syncthreads();
  }
#pragma unroll
  for (int m = 0; m < 4; m++)
#pragma unroll
    for (int n = 0; n < 4; n++)
#pragma unroll
      for (int j = 0; j < 4; j++) {
        int r = brow + wr + m * 16 + l4 * 4 + j;
        int col = bcol + wc + n * 16 + l15;
        float v1 = acc1[m][n][j], v2 = acc2[m][n][j];
        float sg = v1 / (1.0f + expf(-v1));
        G[(size_t)r * N + col] = f2bf(sg * v2);
      }
}

// ---------- RoPE in-place on q (16 heads) and k (8 heads) of qkv[8192][2048] ----------
__global__ __launch_bounds__(256) void rope_k(unsigned short* __restrict__ qkv) {
  int idx = blockIdx.x * 256 + threadIdx.x;  // 8192*24*32 total
  int i = idx & 31;
  int rest = idx >> 5;
  int head = rest % 24;
  int row = rest / 24;
  int t = row & 2047;
  int col = (head < 16) ? (head * 64 + i) : (1024 + (head - 16) * 64 + i);
  size_t base = (size_t)row * 2048 + col;
  float ang = (float)t * exp2f(-(float)i * (13.287712379549449f / 32.0f));
  float s, c;
  sincosf(ang, &s, &c);
  float a = bf2f(qkv[base]), b = bf2f(qkv[base + 32]);
  qkv[base] = f2bf(a * c - b * s);
  qkv[base + 32] = f2bf(b * c + a * s);
}

// ---------- V transpose: qkv v-cols -> vt[(b*8+kh)*64+d][T] ----------
__global__ __launch_bounds__(256) void vtrans_k(const unsigned short* __restrict__ qkv,
                                                unsigned short* __restrict__ vt) {
  __shared__ unsigned short t[64][65];
  const int t0 = blockIdx.x * 64;
  const int bkh = blockIdx.y;
  const int b = bkh >> 3, kh = bkh & 7;
  const int tid = threadIdx.x;
#pragma unroll
  for (int p = 0; p < 16; p++) {
    int flat = p * 256 + tid;
    int tl = flat >> 6, dl = flat & 63;
    t[tl][dl] = qkv[(size_t)(b * 2048 + t0 + tl) * 2048 + 1536 + kh * 64 + dl];
  }
  __syncthreads();
#pragma unroll
  for (int p = 0; p < 16; p++) {
    int flat = p * 256 + tid;
    int dl = flat >> 6, tl = flat & 63;
    vt[((size_t)(b * 8 + kh) * 64 + dl) * 2048 + t0 + tl] = t[tl][dl];
  }
}

// ---------- flash attention (swapped-QK^T, 4 waves/block, no barriers) ----------
// Wave w handles 16 q-rows t = t0 + w*16 + l15.
// QK^T = mfma(A=K, B=Q): D col = t (lane&15), row = s. Softmax s-reduce is
// 8 in-lane values + shfl_xor(16,32). P -> bf16 via v_cvt_pk, per-wave LDS
// buffer (stride 40 shorts, no barriers), b128 read as PV B-frag.
// PV: O^T = mfma(A=Vt, B=P): D col = t, row = d.
__global__ __launch_bounds__(256) void attn_k(const unsigned short* __restrict__ qkv,
                                              const unsigned short* __restrict__ vt,
                                              unsigned short* __restrict__ out) {
  const int blk = blockIdx.x;
  const int tt = blk & 31, bh = blk >> 5;
  const int h = bh & 15, b = bh >> 4;
  const int wid = threadIdx.x >> 6;
  const int lane = threadIdx.x & 63, l15 = lane & 15, l4 = lane >> 4;
  const int t0w = tt * 64 + wid * 16;
  const int kh = h >> 1;

  // Q as B-frag: lane l15 = q-row t, k = l4*8+i over d
  const unsigned short* qbase = qkv + (size_t)(b * 2048 + t0w + l15) * 2048 + h * 64;
  bfrag q0 = *(const bfrag*)(qbase + l4 * 8);
  bfrag q1 = *(const bfrag*)(qbase + 32 + l4 * 8);

  float mrun = -1e30f, lsum = 0.f;
  f4 o[4];
#pragma unroll
  for (int d = 0; d < 4; d++) o[d] = (f4){0.f, 0.f, 0.f, 0.f};

  __shared__ unsigned short P[4][16 * 40];
  unsigned short* Pw = &P[wid][0];
  const unsigned short* vbase = vt + (size_t)(b * 8 + kh) * 64 * 2048;
  const float sc = 0.125f;  // 1/sqrt(64)

  for (int s0 = 0; s0 <= t0w + 15; s0 += 32) {
    // QK^T swapped: A=K (lane l15 = s row), B=Q
    f4 sa[2];
#pragma unroll
    for (int sub = 0; sub < 2; sub++) {
      sa[sub] = (f4){0.f, 0.f, 0.f, 0.f};
      const unsigned short* kb =
          qkv + (size_t)(b * 2048 + s0 + sub * 16 + l15) * 2048 + 1024 + kh * 64;
      bfrag k0 = *(const bfrag*)(kb + l4 * 8);
      bfrag k1 = *(const bfrag*)(kb + 32 + l4 * 8);
      sa[sub] = __builtin_amdgcn_mfma_f32_16x16x32_bf16(k0, q0, sa[sub], 0, 0, 0);
      sa[sub] = __builtin_amdgcn_mfma_f32_16x16x32_bf16(k1, q1, sa[sub], 0, 0, 0);
    }
    // lane holds p[s] for t = t0w + l15, s = s0 + sub*16 + l4*4 + j
    const int t = t0w + l15;
    float p[2][4];
    float mloc = -1e30f;
#pragma unroll
    for (int sub = 0; sub < 2; sub++)
#pragma unroll
      for (int j = 0; j < 4; j++) {
        int s = s0 + sub * 16 + l4 * 4 + j;
        float v = sa[sub][j] * sc;
        if (s > t) v = -1e30f;
        p[sub][j] = v;
        mloc = fmaxf(mloc, v);
      }
    mloc = fmaxf(mloc, __shfl_xor(mloc, 16));
    mloc = fmaxf(mloc, __shfl_xor(mloc, 32));
    float mnew = fmaxf(mrun, mloc);
    float al = __builtin_amdgcn_exp2f((mrun - mnew) * 1.4426950408889634f);
    mrun = mnew;
    float rs = 0.f;
#pragma unroll
    for (int sub = 0; sub < 2; sub++)
#pragma unroll
      for (int j = 0; j < 4; j++) {
        float e = __builtin_amdgcn_exp2f((p[sub][j] - mnew) * 1.4426950408889634f);
        p[sub][j] = e;
        rs += e;
      }
    rs += __shfl_xor(rs, 16);
    rs += __shfl_xor(rs, 32);
    lsum = lsum * al + rs;
#pragma unroll
    for (int d = 0; d < 4; d++)
#pragma unroll
      for (int j = 0; j < 4; j++) o[d][j] *= al;

    // pack P -> bf16, store [t][s] (stride 40 shorts), per-wave buffer, no barrier
#pragma unroll
    for (int sub = 0; sub < 2; sub++) {
      uint2 w;
      w.x = cvt_pk_bf16(p[sub][0], p[sub][1]);
      w.y = cvt_pk_bf16(p[sub][2], p[sub][3]);
      *(uint2*)&Pw[l15 * 40 + sub * 16 + l4 * 4] = w;
    }
    // read back as B-frag: lane l15 = t, k = s = l4*8+i
    bfrag pf = *(const bfrag*)&Pw[l15 * 40 + l4 * 8];
#pragma unroll
    for (int d = 0; d < 4; d++) {
      const unsigned short* vb = vbase + (size_t)(d * 16 + l15) * 2048 + s0 + l4 * 8;
      o[d] = __builtin_amdgcn_mfma_f32_16x16x32_bf16(*(const bfrag*)vb, pf, o[d], 0, 0, 0);
    }
  }
  // o[dblk][j]: col t = l15, row d = dblk*16 + l4*4 + j
  float inv = 1.0f / lsum;
#pragma unroll
  for (int d = 0; d < 4; d++) {
    ushort4 st;
    st.x = f2bf(o[d][0] * inv);
    st.y = f2bf(o[d][1] * inv);
    st.z = f2bf(o[d][2] * inv);
    st.w = f2bf(o[d][3] * inv);
    *(ushort4*)&out[(size_t)(b * 2048 + t0w + l15) * 1024 + h * 64 + d * 16 + l4 * 4] = st;
  }
}

// ---------- launcher ----------
extern "C" void kernel_launch(void* const* d_in, const int* in_sizes, int n_in,
                              void* d_out, int out_size, void* d_ws, size_t ws_size,
                              hipStream_t stream) {
  const float* x = (const float*)d_in[0];
  const float* g1 = (const float*)d_in[1];
  const float* g2 = (const float*)d_in[2];
  const float* wq = (const float*)d_in[3];
  const float* wk = (const float*)d_in[4];
  const float* wv = (const float*)d_in[5];
  const float* wo = (const float*)d_in[6];
  const float* w1 = (const float*)d_in[7];
  const float* w2 = (const float*)d_in[8];
  const float* w3 = (const float*)d_in[9];

  const size_t MB = 1024 * 1024;
  uint8_t* ws = (uint8_t*)d_ws;
  unsigned short* wqkv_t = (unsigned short*)(ws);            // [2048][1024] bf16
  unsigned short* wo_t = (unsigned short*)(ws + 4 * MB);     // [1024][1024]
  unsigned short* w1_t = (unsigned short*)(ws + 6 * MB);     // [4096][1024]
  unsigned short* w2_t = (unsigned short*)(ws + 14 * MB);    // [4096][1024]
  unsigned short* w3_t = (unsigned short*)(ws + 22 * MB);    // [1024][4096]
  unsigned short* hbuf = (unsigned short*)(ws + 30 * MB);    // [8192][1024] h / h2
  unsigned short* qkv = (unsigned short*)(ws + 46 * MB);     // [8192][2048]
  unsigned short* vt = (unsigned short*)(ws + 78 * MB);      // [2048][2048]
  unsigned short* attn_o = (unsigned short*)(ws + 86 * MB);  // [8192][1024]
  unsigned short* gbuf = (unsigned short*)(ws + 46 * MB);    // [8192][4096] reuse qkv/vt/attn_o
  float* x1 = (float*)(ws + 110 * MB);                       // [8192][1024] fp32

  // weights -> bf16 transposed
  tconv_k<<<dim3(32, 32), 256, 0, stream>>>(wq, wqkv_t, 1024, 1024);
  tconv_k<<<dim3(16, 32), 256, 0, stream>>>(wk, wqkv_t + (size_t)1024 * 1024, 1024, 512);
  tconv_k<<<dim3(16, 32), 256, 0, stream>>>(wv, wqkv_t + (size_t)1536 * 1024, 1024, 512);
  tconv_k<<<dim3(32, 32), 256, 0, stream>>>(wo, wo_t, 1024, 1024);
  tconv_k<<<dim3(128, 32), 256, 0, stream>>>(w1, w1_t, 1024, 4096);
  tconv_k<<<dim3(128, 32), 256, 0, stream>>>(w2, w2_t, 1024, 4096);
  tconv_k<<<dim3(32, 128), 256, 0, stream>>>(w3, w3_t, 4096, 1024);

  rmsnorm_k<<<8192, 256, 0, stream>>>(x, g1, hbuf);
  gemm_k<0><<<dim3(64, 16), 256, 0, stream>>>(hbuf, wqkv_t, 8192, 2048, 1024, qkv, nullptr);
  rope_k<<<24576, 256, 0, stream>>>(qkv);
  vtrans_k<<<dim3(32, 32), 256, 0, stream>>>(qkv, vt);
  attn_k<<<2048, 256, 0, stream>>>(qkv, vt, attn_o);
  gemm_k<1><<<dim3(64, 8), 256, 0, stream>>>(attn_o, wo_t, 8192, 1024, 1024, x1, x);
  rmsnorm_k<<<8192, 256, 0, stream>>>(x1, g2, hbuf);
  ffn1_k<<<dim3(64, 32), 256, 0, stream>>>(hbuf, w1_t, w2_t, gbuf, 8192, 4096, 1024);
  gemm_k<1><<<dim3(64, 8), 256, 0, stream>>>(gbuf, w3_t, 8192, 1024, 4096, (float*)d_out, x1);
}

// Round 5
// 775.675 us; speedup vs baseline: 1.4657x; 1.4657x over previous
//
#include <hip/hip_runtime.h>
#include <cstdint>

// ---------- types / helpers ----------
typedef __attribute__((ext_vector_type(8))) short bfrag;   // 8 bf16 in 4 VGPRs
typedef __attribute__((ext_vector_type(4))) float f4;

typedef __attribute__((address_space(1))) const void* gas_t;
typedef __attribute__((address_space(3))) void* las_t;

__device__ __forceinline__ void gload16(const void* g, void* l) {
  __builtin_amdgcn_global_load_lds((gas_t)g, (las_t)l, 16, 0, 0);
}

__device__ __forceinline__ unsigned short f2bf(float f) {
  union { float f; unsigned u; } v; v.f = f;
  unsigned r = v.u + 0x7fffu + ((v.u >> 16) & 1u);
  return (unsigned short)(r >> 16);
}
__device__ __forceinline__ float bf2f(unsigned short b) {
  union { unsigned u; float f; } v; v.u = ((unsigned)b) << 16;
  return v.f;
}
__device__ __forceinline__ unsigned cvt_pk_bf16(float lo, float hi) {
  unsigned r;
  asm("v_cvt_pk_bf16_f32 %0, %1, %2" : "=v"(r) : "v"(lo), "v"(hi));
  return r;
}

// ---------- transpose+convert: in[R][C] fp32 -> out[C][R] bf16 ----------
__global__ __launch_bounds__(256) void tconv_k(const float* __restrict__ in,
                                               unsigned short* __restrict__ out,
                                               int R, int C) {
  __shared__ unsigned short t[32][33];
  const int c0 = blockIdx.x * 32, r0 = blockIdx.y * 32;
  const int tid = threadIdx.x;
#pragma unroll
  for (int p = 0; p < 4; p++) {
    int flat = p * 256 + tid;
    int r = flat >> 5, c = flat & 31;
    t[r][c] = f2bf(in[(size_t)(r0 + r) * C + c0 + c]);
  }
  __syncthreads();
#pragma unroll
  for (int p = 0; p < 4; p++) {
    int flat = p * 256 + tid;
    int cc = flat >> 5, rr = flat & 31;
    out[(size_t)(c0 + cc) * R + r0 + rr] = t[rr][cc];
  }
}

// ---------- RMSNorm: x fp32 [rows][1024] -> bf16 ----------
__global__ __launch_bounds__(256) void rmsnorm_k(const float* __restrict__ x,
                                                 const float* __restrict__ g,
                                                 unsigned short* __restrict__ out) {
  const int row = blockIdx.x, tid = threadIdx.x;
  const float4 v = ((const float4*)(x + (size_t)row * 1024))[tid];
  float ss = v.x * v.x + v.y * v.y + v.z * v.z + v.w * v.w;
#pragma unroll
  for (int off = 1; off < 64; off <<= 1) ss += __shfl_xor(ss, off);
  __shared__ float red[4];
  if ((tid & 63) == 0) red[tid >> 6] = ss;
  __syncthreads();
  float tot = red[0] + red[1] + red[2] + red[3];
  float sc = rsqrtf(tot * (1.0f / 1024.0f) + 1e-6f);
  const float4 gv = ((const float4*)g)[tid];
  ushort4 o;
  o.x = f2bf(v.x * sc * gv.x);
  o.y = f2bf(v.y * sc * gv.y);
  o.z = f2bf(v.z * sc * gv.z);
  o.w = f2bf(v.w * sc * gv.w);
  ((ushort4*)out)[(size_t)row * 256 + tid] = o;
}

// ---------- GEMM: C[M,N] = A[M,K](bf16) @ Bt[N,K](bf16)^T ----------
// MODE 0: write bf16 C.  MODE 1: write fp32 C = acc + resid.
template <int MODE>
__global__ __launch_bounds__(256) void gemm_k(const unsigned short* __restrict__ A,
                                              const unsigned short* __restrict__ Bt,
                                              int M, int N, int K,
                                              void* __restrict__ Cout,
                                              const float* __restrict__ resid) {
  __shared__ unsigned short As[128 * 32];
  __shared__ unsigned short Bs[128 * 32];
  const int tid = threadIdx.x;
  const int wid = tid >> 6, lane = tid & 63;
  const int l15 = lane & 15, l4 = lane >> 4;
  const int brow = blockIdx.x * 128, bcol = blockIdx.y * 128;
  const int wr = (wid >> 1) * 64, wc = (wid & 1) * 64;
  f4 acc[4][4];
#pragma unroll
  for (int m = 0; m < 4; m++)
#pragma unroll
    for (int n = 0; n < 4; n++) acc[m][n] = (f4){0.f, 0.f, 0.f, 0.f};

  for (int k0 = 0; k0 < K; k0 += 32) {
#pragma unroll
    for (int c = 0; c < 2; c++) {
      int base = c * 256 + wid * 64;
      int e = base + lane;
      int row = e >> 2, col = (e & 3) * 8;
      gload16(A + (size_t)(brow + row) * K + k0 + col, &As[base * 8]);
      gload16(Bt + (size_t)(bcol + row) * K + k0 + col, &Bs[base * 8]);
    }
    __syncthreads();
    bfrag a[4], b[4];
#pragma unroll
    for (int m = 0; m < 4; m++) a[m] = *(const bfrag*)&As[(wr + m * 16 + l15) * 32 + l4 * 8];
#pragma unroll
    for (int n = 0; n < 4; n++) b[n] = *(const bfrag*)&Bs[(wc + n * 16 + l15) * 32 + l4 * 8];
#pragma unroll
    for (int m = 0; m < 4; m++)
#pragma unroll
      for (int n = 0; n < 4; n++)
        acc[m][n] = __builtin_amdgcn_mfma_f32_16x16x32_bf16(a[m], b[n], acc[m][n], 0, 0, 0);
    __syncthreads();
  }
#pragma unroll
  for (int m = 0; m < 4; m++)
#pragma unroll
    for (int n = 0; n < 4; n++)
#pragma unroll
      for (int j = 0; j < 4; j++) {
        int r = brow + wr + m * 16 + l4 * 4 + j;
        int col = bcol + wc + n * 16 + l15;
        if (MODE == 0) {
          ((unsigned short*)Cout)[(size_t)r * N + col] = f2bf(acc[m][n][j]);
        } else {
          ((float*)Cout)[(size_t)r * N + col] = acc[m][n][j] + resid[(size_t)r * N + col];
        }
      }
}

// ---------- fused FFN1: G = silu(A@W1t^T) * (A@W2t^T), bf16 out ----------
__global__ __launch_bounds__(256) void ffn1_k(const unsigned short* __restrict__ A,
                                              const unsigned short* __restrict__ B1t,
                                              const unsigned short* __restrict__ B2t,
                                              unsigned short* __restrict__ G,
                                              int M, int N, int K) {
  __shared__ unsigned short As[128 * 32];
  __shared__ unsigned short B1s[128 * 32];
  __shared__ unsigned short B2s[128 * 32];
  const int tid = threadIdx.x;
  const int wid = tid >> 6, lane = tid & 63;
  const int l15 = lane & 15, l4 = lane >> 4;
  const int brow = blockIdx.x * 128, bcol = blockIdx.y * 128;
  const int wr = (wid >> 1) * 64, wc = (wid & 1) * 64;
  f4 acc1[4][4], acc2[4][4];
#pragma unroll
  for (int m = 0; m < 4; m++)
#pragma unroll
    for (int n = 0; n < 4; n++) {
      acc1[m][n] = (f4){0.f, 0.f, 0.f, 0.f};
      acc2[m][n] = (f4){0.f, 0.f, 0.f, 0.f};
    }

  for (int k0 = 0; k0 < K; k0 += 32) {
#pragma unroll
    for (int c = 0; c < 2; c++) {
      int base = c * 256 + wid * 64;
      int e = base + lane;
      int row = e >> 2, col = (e & 3) * 8;
      gload16(A + (size_t)(brow + row) * K + k0 + col, &As[base * 8]);
      gload16(B1t + (size_t)(bcol + row) * K + k0 + col, &B1s[base * 8]);
      gload16(B2t + (size_t)(bcol + row) * K + k0 + col, &B2s[base * 8]);
    }
    __syncthreads();
    bfrag a[4], b1[4], b2[4];
#pragma unroll
    for (int m = 0; m < 4; m++) a[m] = *(const bfrag*)&As[(wr + m * 16 + l15) * 32 + l4 * 8];
#pragma unroll
    for (int n = 0; n < 4; n++) {
      b1[n] = *(const bfrag*)&B1s[(wc + n * 16 + l15) * 32 + l4 * 8];
      b2[n] = *(const bfrag*)&B2s[(wc + n * 16 + l15) * 32 + l4 * 8];
    }
#pragma unroll
    for (int m = 0; m < 4; m++)
#pragma unroll
      for (int n = 0; n < 4; n++) {
        acc1[m][n] = __builtin_amdgcn_mfma_f32_16x16x32_bf16(a[m], b1[n], acc1[m][n], 0, 0, 0);
        acc2[m][n] = __builtin_amdgcn_mfma_f32_16x16x32_bf16(a[m], b2[n], acc2[m][n], 0, 0, 0);
      }
    __syncthreads();
  }
#pragma unroll
  for (int m = 0; m < 4; m++)
#pragma unroll
    for (int n = 0; n < 4; n++)
#pragma unroll
      for (int j = 0; j < 4; j++) {
        int r = brow + wr + m * 16 + l4 * 4 + j;
        int col = bcol + wc + n * 16 + l15;
        float v1 = acc1[m][n][j], v2 = acc2[m][n][j];
        float sg = v1 / (1.0f + expf(-v1));
        G[(size_t)r * N + col] = f2bf(sg * v2);
      }
}

// ---------- RoPE in-place on q (16 heads) and k (8 heads) of qkv[8192][2048] ----------
__global__ __launch_bounds__(256) void rope_k(unsigned short* __restrict__ qkv) {
  int idx = blockIdx.x * 256 + threadIdx.x;  // 8192*24*32 total
  int i = idx & 31;
  int rest = idx >> 5;
  int head = rest % 24;
  int row = rest / 24;
  int t = row & 2047;
  int col = (head < 16) ? (head * 64 + i) : (1024 + (head - 16) * 64 + i);
  size_t base = (size_t)row * 2048 + col;
  float ang = (float)t * exp2f(-(float)i * (13.287712379549449f / 32.0f));
  float s, c;
  sincosf(ang, &s, &c);
  float a = bf2f(qkv[base]), b = bf2f(qkv[base + 32]);
  qkv[base] = f2bf(a * c - b * s);
  qkv[base + 32] = f2bf(b * c + a * s);
}

// ---------- V transpose: qkv v-cols -> vt[(b*8+kh)*64+d][T] ----------
__global__ __launch_bounds__(256) void vtrans_k(const unsigned short* __restrict__ qkv,
                                                unsigned short* __restrict__ vt) {
  __shared__ unsigned short t[64][65];
  const int t0 = blockIdx.x * 64;
  const int bkh = blockIdx.y;
  const int b = bkh >> 3, kh = bkh & 7;
  const int tid = threadIdx.x;
#pragma unroll
  for (int p = 0; p < 16; p++) {
    int flat = p * 256 + tid;
    int tl = flat >> 6, dl = flat & 63;
    t[tl][dl] = qkv[(size_t)(b * 2048 + t0 + tl) * 2048 + 1536 + kh * 64 + dl];
  }
  __syncthreads();
#pragma unroll
  for (int p = 0; p < 16; p++) {
    int flat = p * 256 + tid;
    int dl = flat >> 6, tl = flat & 63;
    vt[((size_t)(b * 8 + kh) * 64 + dl) * 2048 + t0 + tl] = t[tl][dl];
  }
}

// ---------- flash attention: LDS-staged KV, double-buffered, GQA-shared ----------
// Block = (b, kh, 32-row q-tile). 4 waves: w0,w1 -> head 2kh rows {0,16};
// w2,w3 -> head 2kh+1 rows {0,16}. K/V tiles [64][64] bf16 staged via
// global_load_lds (16B chunks) with XOR-swizzled SOURCE (slot ^= row&7) so
// fragment reads are bank-uniform. Counted vmcnt(4) pipeline, raw barriers.
// QK^T swapped (A=K, B=Q): lane&15 = q-row t; softmax s-reduce is 16 in-lane
// + shfl_xor(16,32). PV: O^T = mfma(A=Vt-frag, B=P-frag).
__global__ __launch_bounds__(256) void attn_k(const unsigned short* __restrict__ qkv,
                                              const unsigned short* __restrict__ vt,
                                              unsigned short* __restrict__ out) {
  const int blk = blockIdx.x;
  const int bkh = blk & 31;          // b*8+kh  (same-kh blocks -> same XCD)
  const int tile = 63 - (blk >> 5);  // long tiles dispatch first
  const int b = bkh >> 3, kh = bkh & 7;
  const int tid = threadIdx.x;
  const int w = tid >> 6, lane = tid & 63, l15 = lane & 15, l4 = lane >> 4;
  const int h = kh * 2 + (w >> 1);
  const int t0w = tile * 32 + (w & 1) * 16;
  const int thi = tile * 32 + 31;

  __shared__ unsigned short KT[2][4096];  // [buf][64 rows][64 d] swizzled chunks
  __shared__ unsigned short VT[2][4096];  // [buf][64 d][64 s] swizzled chunks
  __shared__ unsigned short P[4][16 * 72];
  unsigned short* Pw = &P[w][0];

  // Q as B-frag: lane l15 = q-row t, k = l4*8+i over d
  const unsigned short* qbase = qkv + (size_t)(b * 2048 + t0w + l15) * 2048 + h * 64;
  bfrag q0 = *(const bfrag*)(qbase + l4 * 8);
  bfrag q1 = *(const bfrag*)(qbase + 32 + l4 * 8);

  float mrun = -1e30f, lsum = 0.f;
  f4 o[4];
#pragma unroll
  for (int d = 0; d < 4; d++) o[d] = (f4){0.f, 0.f, 0.f, 0.f};

  const unsigned short* vbase = vt + (size_t)(b * 8 + kh) * 64 * 2048;
  const float sc2 = 0.125f * 1.4426950408889634f;  // 1/sqrt(64) * log2(e)

  // stage K/V tile for s0 into buf: 512 chunks each, 2 rounds, 4 loads/thread
  auto STAGE = [&](int buf, int s0) {
#pragma unroll
    for (int p = 0; p < 2; ++p) {
      int c = p * 256 + w * 64 + lane;
      int r = c >> 3, sl = (c & 7) ^ (r & 7);
      gload16(qkv + (size_t)(b * 2048 + s0 + r) * 2048 + 1024 + kh * 64 + sl * 8,
              &KT[buf][(p * 256 + w * 64) * 8]);
      gload16(vbase + (size_t)r * 2048 + s0 + sl * 8,
              &VT[buf][(p * 256 + w * 64) * 8]);
    }
  };

  STAGE(0, 0);
  int cur = 0;
  for (int s0 = 0; s0 <= thi; s0 += 64) {
    if (s0 + 64 <= thi) {
      STAGE(cur ^ 1, s0 + 64);
      asm volatile("s_waitcnt vmcnt(4)" ::: "memory");
    } else {
      asm volatile("s_waitcnt vmcnt(0)" ::: "memory");
    }
    __builtin_amdgcn_s_barrier();

    // ---- QK^T: 4 sub-tiles of 16 s ----
    f4 sa[4];
#pragma unroll
    for (int sub = 0; sub < 4; ++sub) {
      int rb = sub * 16 + l15;
      int x = rb & 7;
      bfrag k0 = *(const bfrag*)&KT[cur][(rb * 8 + (l4 ^ x)) * 8];
      bfrag k1 = *(const bfrag*)&KT[cur][(rb * 8 + ((l4 + 4) ^ x)) * 8];
      f4 z = (f4){0.f, 0.f, 0.f, 0.f};
      z = __builtin_amdgcn_mfma_f32_16x16x32_bf16(k0, q0, z, 0, 0, 0);
      z = __builtin_amdgcn_mfma_f32_16x16x32_bf16(k1, q1, z, 0, 0, 0);
      sa[sub] = z;
    }
    // ---- softmax (log2 domain), t = t0w + l15 ----
    const int t = t0w + l15;
    float pv[4][4];
    float mloc = -1e30f;
#pragma unroll
    for (int sub = 0; sub < 4; ++sub)
#pragma unroll
      for (int j = 0; j < 4; ++j) {
        int s = s0 + sub * 16 + l4 * 4 + j;
        float v = sa[sub][j] * sc2;
        if (s > t) v = -1e30f;
        pv[sub][j] = v;
        mloc = fmaxf(mloc, v);
      }
    mloc = fmaxf(mloc, __shfl_xor(mloc, 16));
    mloc = fmaxf(mloc, __shfl_xor(mloc, 32));
    float mnew = fmaxf(mrun, mloc);
    float al = __builtin_amdgcn_exp2f(mrun - mnew);
    mrun = mnew;
    float rs = 0.f;
#pragma unroll
    for (int sub = 0; sub < 4; ++sub)
#pragma unroll
      for (int j = 0; j < 4; ++j) {
        float e = __builtin_amdgcn_exp2f(pv[sub][j] - mnew);
        pv[sub][j] = e;
        rs += e;
      }
    rs += __shfl_xor(rs, 16);
    rs += __shfl_xor(rs, 32);
    lsum = lsum * al + rs;
#pragma unroll
    for (int d = 0; d < 4; d++)
#pragma unroll
      for (int j = 0; j < 4; j++) o[d][j] *= al;

    // ---- P -> bf16 -> per-wave LDS [16 t][64 s] (stride 72) ----
#pragma unroll
    for (int sub = 0; sub < 4; ++sub) {
      uint2 u;
      u.x = cvt_pk_bf16(pv[sub][0], pv[sub][1]);
      u.y = cvt_pk_bf16(pv[sub][2], pv[sub][3]);
      *(uint2*)&Pw[l15 * 72 + sub * 16 + l4 * 4] = u;
    }
    // ---- PV: O^T += Vt-frag @ P-frag ----
#pragma unroll
    for (int sh = 0; sh < 2; ++sh) {
      bfrag pf = *(const bfrag*)&Pw[l15 * 72 + sh * 32 + l4 * 8];
#pragma unroll
      for (int dblk = 0; dblk < 4; ++dblk) {
        int d = dblk * 16 + l15;
        bfrag vf = *(const bfrag*)&VT[cur][(d * 8 + ((sh * 4 + l4) ^ (d & 7))) * 8];
        o[dblk] = __builtin_amdgcn_mfma_f32_16x16x32_bf16(vf, pf, o[dblk], 0, 0, 0);
      }
    }
    asm volatile("s_waitcnt lgkmcnt(0)" ::: "memory");
    __builtin_amdgcn_s_barrier();
    cur ^= 1;
  }
  // o[dblk][j]: col t = l15, row d = dblk*16 + l4*4 + j
  float inv = 1.0f / lsum;
#pragma unroll
  for (int d = 0; d < 4; d++) {
    ushort4 st;
    st.x = f2bf(o[d][0] * inv);
    st.y = f2bf(o[d][1] * inv);
    st.z = f2bf(o[d][2] * inv);
    st.w = f2bf(o[d][3] * inv);
    *(ushort4*)&out[(size_t)(b * 2048 + t0w + l15) * 1024 + h * 64 + d * 16 + l4 * 4] = st;
  }
}

// ---------- launcher ----------
extern "C" void kernel_launch(void* const* d_in, const int* in_sizes, int n_in,
                              void* d_out, int out_size, void* d_ws, size_t ws_size,
                              hipStream_t stream) {
  const float* x = (const float*)d_in[0];
  const float* g1 = (const float*)d_in[1];
  const float* g2 = (const float*)d_in[2];
  const float* wq = (const float*)d_in[3];
  const float* wk = (const float*)d_in[4];
  const float* wv = (const float*)d_in[5];
  const float* wo = (const float*)d_in[6];
  const float* w1 = (const float*)d_in[7];
  const float* w2 = (const float*)d_in[8];
  const float* w3 = (const float*)d_in[9];

  const size_t MB = 1024 * 1024;
  uint8_t* ws = (uint8_t*)d_ws;
  unsigned short* wqkv_t = (unsigned short*)(ws);            // [2048][1024] bf16
  unsigned short* wo_t = (unsigned short*)(ws + 4 * MB);     // [1024][1024]
  unsigned short* w1_t = (unsigned short*)(ws + 6 * MB);     // [4096][1024]
  unsigned short* w2_t = (unsigned short*)(ws + 14 * MB);    // [4096][1024]
  unsigned short* w3_t = (unsigned short*)(ws + 22 * MB);    // [1024][4096]
  unsigned short* hbuf = (unsigned short*)(ws + 30 * MB);    // [8192][1024] h / h2
  unsigned short* qkv = (unsigned short*)(ws + 46 * MB);     // [8192][2048]
  unsigned short* vt = (unsigned short*)(ws + 78 * MB);      // [2048][2048]
  unsigned short* attn_o = (unsigned short*)(ws + 86 * MB);  // [8192][1024]
  unsigned short* gbuf = (unsigned short*)(ws + 46 * MB);    // [8192][4096] reuse qkv/vt/attn_o
  float* x1 = (float*)(ws + 110 * MB);                       // [8192][1024] fp32

  // weights -> bf16 transposed
  tconv_k<<<dim3(32, 32), 256, 0, stream>>>(wq, wqkv_t, 1024, 1024);
  tconv_k<<<dim3(16, 32), 256, 0, stream>>>(wk, wqkv_t + (size_t)1024 * 1024, 1024, 512);
  tconv_k<<<dim3(16, 32), 256, 0, stream>>>(wv, wqkv_t + (size_t)1536 * 1024, 1024, 512);
  tconv_k<<<dim3(32, 32), 256, 0, stream>>>(wo, wo_t, 1024, 1024);
  tconv_k<<<dim3(128, 32), 256, 0, stream>>>(w1, w1_t, 1024, 4096);
  tconv_k<<<dim3(128, 32), 256, 0, stream>>>(w2, w2_t, 1024, 4096);
  tconv_k<<<dim3(32, 128), 256, 0, stream>>>(w3, w3_t, 4096, 1024);

  rmsnorm_k<<<8192, 256, 0, stream>>>(x, g1, hbuf);
  gemm_k<0><<<dim3(64, 16), 256, 0, stream>>>(hbuf, wqkv_t, 8192, 2048, 1024, qkv, nullptr);
  rope_k<<<24576, 256, 0, stream>>>(qkv);
  vtrans_k<<<dim3(32, 32), 256, 0, stream>>>(qkv, vt);
  attn_k<<<2048, 256, 0, stream>>>(qkv, vt, attn_o);
  gemm_k<1><<<dim3(64, 8), 256, 0, stream>>>(attn_o, wo_t, 8192, 1024, 1024, x1, x);
  rmsnorm_k<<<8192, 256, 0, stream>>>(x1, g2, hbuf);
  ffn1_k<<<dim3(64, 32), 256, 0, stream>>>(hbuf, w1_t, w2_t, gbuf, 8192, 4096, 1024);
  gemm_k<1><<<dim3(64, 8), 256, 0, stream>>>(gbuf, w3_t, 8192, 1024, 4096, (float*)d_out, x1);
}

// Round 7
// 648.522 us; speedup vs baseline: 1.7530x; 1.1961x over previous
//
#include <hip/hip_runtime.h>
#include <cstdint>

// ---------- types / helpers ----------
typedef __attribute__((ext_vector_type(8))) short bfrag;   // 8 bf16 in 4 VGPRs
typedef __attribute__((ext_vector_type(4))) float f4;

typedef __attribute__((address_space(1))) const void* gas_t;
typedef __attribute__((address_space(3))) void* las_t;

__device__ __forceinline__ void gload16(const void* g, void* l) {
  __builtin_amdgcn_global_load_lds((gas_t)g, (las_t)l, 16, 0, 0);
}

__device__ __forceinline__ unsigned short f2bf(float f) {
  union { float f; unsigned u; } v; v.f = f;
  unsigned r = v.u + 0x7fffu + ((v.u >> 16) & 1u);
  return (unsigned short)(r >> 16);
}
__device__ __forceinline__ float bf2f(unsigned short b) {
  union { unsigned u; float f; } v; v.u = ((unsigned)b) << 16;
  return v.f;
}
__device__ __forceinline__ unsigned cvt_pk_bf16(float lo, float hi) {
  unsigned r;
  asm("v_cvt_pk_bf16_f32 %0, %1, %2" : "=v"(r) : "v"(lo), "v"(hi));
  return r;
}

// XCD-aware bijective block swizzle (nwg % 8 == 0 for all our grids)
__device__ __forceinline__ void xcd_swz(int& bx, int& by) {
  int gx = gridDim.x;
  int lid = blockIdx.y * gx + blockIdx.x;
  int nwg = gx * gridDim.y;
  int swz = (lid & 7) * (nwg >> 3) + (lid >> 3);
  bx = swz % gx;
  by = swz / gx;
}

// ---------- transpose+convert: in[R][C] fp32 -> out[C][R] bf16 ----------
__global__ __launch_bounds__(256) void tconv_k(const float* __restrict__ in,
                                               unsigned short* __restrict__ out,
                                               int R, int C) {
  __shared__ unsigned short t[32][33];
  const int c0 = blockIdx.x * 32, r0 = blockIdx.y * 32;
  const int tid = threadIdx.x;
#pragma unroll
  for (int p = 0; p < 4; p++) {
    int flat = p * 256 + tid;
    int r = flat >> 5, c = flat & 31;
    t[r][c] = f2bf(in[(size_t)(r0 + r) * C + c0 + c]);
  }
  __syncthreads();
#pragma unroll
  for (int p = 0; p < 4; p++) {
    int flat = p * 256 + tid;
    int cc = flat >> 5, rr = flat & 31;
    out[(size_t)(c0 + cc) * R + r0 + rr] = t[rr][cc];
  }
}

// ---------- RMSNorm: x fp32 [rows][1024] -> bf16 ----------
__global__ __launch_bounds__(256) void rmsnorm_k(const float* __restrict__ x,
                                                 const float* __restrict__ g,
                                                 unsigned short* __restrict__ out) {
  const int row = blockIdx.x, tid = threadIdx.x;
  const float4 v = ((const float4*)(x + (size_t)row * 1024))[tid];
  float ss = v.x * v.x + v.y * v.y + v.z * v.z + v.w * v.w;
#pragma unroll
  for (int off = 1; off < 64; off <<= 1) ss += __shfl_xor(ss, off);
  __shared__ float red[4];
  if ((tid & 63) == 0) red[tid >> 6] = ss;
  __syncthreads();
  float tot = red[0] + red[1] + red[2] + red[3];
  float sc = rsqrtf(tot * (1.0f / 1024.0f) + 1e-6f);
  const float4 gv = ((const float4*)g)[tid];
  ushort4 o;
  o.x = f2bf(v.x * sc * gv.x);
  o.y = f2bf(v.y * sc * gv.y);
  o.z = f2bf(v.z * sc * gv.z);
  o.w = f2bf(v.w * sc * gv.w);
  ((ushort4*)out)[(size_t)row * 256 + tid] = o;
}

// ---------- GEMM: C[M,N] = A[M,K](bf16) @ Bt[N,K](bf16)^T ----------
// 128x128 tile, XOR-swizzled LDS chunks (4-way max bank aliasing), XCD swizzle.
// MODE 0: write bf16 C.  MODE 1: write fp32 C = acc + resid.
template <int MODE>
__global__ __launch_bounds__(256) void gemm_k(const unsigned short* __restrict__ A,
                                              const unsigned short* __restrict__ Bt,
                                              int M, int N, int K,
                                              void* __restrict__ Cout,
                                              const float* __restrict__ resid) {
  __shared__ unsigned short As[128 * 32];
  __shared__ unsigned short Bs[128 * 32];
  const int tid = threadIdx.x;
  const int wid = tid >> 6, lane = tid & 63;
  const int l15 = lane & 15, l4 = lane >> 4;
  int bx, by;
  xcd_swz(bx, by);
  const int brow = bx * 128, bcol = by * 128;
  const int wr = (wid >> 1) * 64, wc = (wid & 1) * 64;
  const int x15 = l15 & 3;  // row&3 for fragment rows
  f4 acc[4][4];
#pragma unroll
  for (int m = 0; m < 4; m++)
#pragma unroll
    for (int n = 0; n < 4; n++) acc[m][n] = (f4){0.f, 0.f, 0.f, 0.f};

  for (int k0 = 0; k0 < K; k0 += 32) {
#pragma unroll
    for (int c = 0; c < 2; c++) {
      int slot = c * 256 + tid;
      int r = slot >> 2, cp = slot & 3;
      int sc = (cp ^ (r & 3)) * 8;
      gload16(A + (size_t)(brow + r) * K + k0 + sc, &As[slot * 8]);
      gload16(Bt + (size_t)(bcol + r) * K + k0 + sc, &Bs[slot * 8]);
    }
    __syncthreads();
    bfrag a[4], b[4];
#pragma unroll
    for (int m = 0; m < 4; m++)
      a[m] = *(const bfrag*)&As[(wr + m * 16 + l15) * 32 + (l4 ^ x15) * 8];
#pragma unroll
    for (int n = 0; n < 4; n++)
      b[n] = *(const bfrag*)&Bs[(wc + n * 16 + l15) * 32 + (l4 ^ x15) * 8];
#pragma unroll
    for (int m = 0; m < 4; m++)
#pragma unroll
      for (int n = 0; n < 4; n++)
        acc[m][n] = __builtin_amdgcn_mfma_f32_16x16x32_bf16(a[m], b[n], acc[m][n], 0, 0, 0);
    __syncthreads();
  }
#pragma unroll
  for (int m = 0; m < 4; m++)
#pragma unroll
    for (int n = 0; n < 4; n++)
#pragma unroll
      for (int j = 0; j < 4; j++) {
        int r = brow + wr + m * 16 + l4 * 4 + j;
        int col = bcol + wc + n * 16 + l15;
        if (MODE == 0) {
          ((unsigned short*)Cout)[(size_t)r * N + col] = f2bf(acc[m][n][j]);
        } else {
          ((float*)Cout)[(size_t)r * N + col] = acc[m][n][j] + resid[(size_t)r * N + col];
        }
      }
}

// ---------- fused FFN1: G = silu(A@W1t^T) * (A@W2t^T), bf16 out ----------
// 128x64 tile (acc 64 regs -> 2 waves/SIMD), XOR-swizzled LDS, XCD swizzle.
__global__ __launch_bounds__(256, 2) void ffn1_k(const unsigned short* __restrict__ A,
                                                 const unsigned short* __restrict__ B1t,
                                                 const unsigned short* __restrict__ B2t,
                                                 unsigned short* __restrict__ G,
                                                 int M, int N, int K) {
  __shared__ unsigned short As[128 * 32];
  __shared__ unsigned short B1s[64 * 32];
  __shared__ unsigned short B2s[64 * 32];
  const int tid = threadIdx.x;
  const int wid = tid >> 6, lane = tid & 63;
  const int l15 = lane & 15, l4 = lane >> 4;
  int bx, by;
  xcd_swz(bx, by);
  const int brow = bx * 128, bcol = by * 64;
  const int wr = (wid >> 1) * 64, wc = (wid & 1) * 32;
  const int x15 = l15 & 3;
  f4 acc1[4][2], acc2[4][2];
#pragma unroll
  for (int m = 0; m < 4; m++)
#pragma unroll
    for (int n = 0; n < 2; n++) {
      acc1[m][n] = (f4){0.f, 0.f, 0.f, 0.f};
      acc2[m][n] = (f4){0.f, 0.f, 0.f, 0.f};
    }

  for (int k0 = 0; k0 < K; k0 += 32) {
#pragma unroll
    for (int p = 0; p < 2; p++) {
      int slot = p * 256 + tid;
      int r = slot >> 2, cp = slot & 3;
      int sc = (cp ^ (r & 3)) * 8;
      gload16(A + (size_t)(brow + r) * K + k0 + sc, &As[slot * 8]);
    }
    {
      int r = tid >> 2, cp = tid & 3;
      int sc = (cp ^ (r & 3)) * 8;
      gload16(B1t + (size_t)(bcol + r) * K + k0 + sc, &B1s[tid * 8]);
      gload16(B2t + (size_t)(bcol + r) * K + k0 + sc, &B2s[tid * 8]);
    }
    __syncthreads();
    bfrag a[4], b1[2], b2[2];
#pragma unroll
    for (int m = 0; m < 4; m++)
      a[m] = *(const bfrag*)&As[(wr + m * 16 + l15) * 32 + (l4 ^ x15) * 8];
#pragma unroll
    for (int n = 0; n < 2; n++) {
      b1[n] = *(const bfrag*)&B1s[(wc + n * 16 + l15) * 32 + (l4 ^ x15) * 8];
      b2[n] = *(const bfrag*)&B2s[(wc + n * 16 + l15) * 32 + (l4 ^ x15) * 8];
    }
#pragma unroll
    for (int m = 0; m < 4; m++)
#pragma unroll
      for (int n = 0; n < 2; n++) {
        acc1[m][n] = __builtin_amdgcn_mfma_f32_16x16x32_bf16(a[m], b1[n], acc1[m][n], 0, 0, 0);
        acc2[m][n] = __builtin_amdgcn_mfma_f32_16x16x32_bf16(a[m], b2[n], acc2[m][n], 0, 0, 0);
      }
    __syncthreads();
  }
#pragma unroll
  for (int m = 0; m < 4; m++)
#pragma unroll
    for (int n = 0; n < 2; n++)
#pragma unroll
      for (int j = 0; j < 4; j++) {
        int r = brow + wr + m * 16 + l4 * 4 + j;
        int col = bcol + wc + n * 16 + l15;
        float v1 = acc1[m][n][j], v2 = acc2[m][n][j];
        float sg = v1 / (1.0f + expf(-v1));
        G[(size_t)r * N + col] = f2bf(sg * v2);
      }
}

// ---------- RoPE in-place on q (16 heads) and k (8 heads) of qkv[8192][2048] ----------
__global__ __launch_bounds__(256) void rope_k(unsigned short* __restrict__ qkv) {
  int idx = blockIdx.x * 256 + threadIdx.x;  // 8192*24*32 total
  int i = idx & 31;
  int rest = idx >> 5;
  int head = rest % 24;
  int row = rest / 24;
  int t = row & 2047;
  int col = (head < 16) ? (head * 64 + i) : (1024 + (head - 16) * 64 + i);
  size_t base = (size_t)row * 2048 + col;
  float ang = (float)t * exp2f(-(float)i * (13.287712379549449f / 32.0f));
  float s, c;
  sincosf(ang, &s, &c);
  float a = bf2f(qkv[base]), b = bf2f(qkv[base + 32]);
  qkv[base] = f2bf(a * c - b * s);
  qkv[base + 32] = f2bf(b * c + a * s);
}

// ---------- V transpose: qkv v-cols -> vt[(b*8+kh)*64+d][T] ----------
__global__ __launch_bounds__(256) void vtrans_k(const unsigned short* __restrict__ qkv,
                                                unsigned short* __restrict__ vt) {
  __shared__ unsigned short t[64][65];
  const int t0 = blockIdx.x * 64;
  const int bkh = blockIdx.y;
  const int b = bkh >> 3, kh = bkh & 7;
  const int tid = threadIdx.x;
#pragma unroll
  for (int p = 0; p < 16; p++) {
    int flat = p * 256 + tid;
    int tl = flat >> 6, dl = flat & 63;
    t[tl][dl] = qkv[(size_t)(b * 2048 + t0 + tl) * 2048 + 1536 + kh * 64 + dl];
  }
  __syncthreads();
#pragma unroll
  for (int p = 0; p < 16; p++) {
    int flat = p * 256 + tid;
    int dl = flat >> 6, tl = flat & 63;
    vt[((size_t)(b * 8 + kh) * 64 + dl) * 2048 + t0 + tl] = t[tl][dl];
  }
}

// ---------- flash attention: LDS-staged KV, double-buffered, GQA-shared ----------
__global__ __launch_bounds__(256) void attn_k(const unsigned short* __restrict__ qkv,
                                              const unsigned short* __restrict__ vt,
                                              unsigned short* __restrict__ out) {
  const int blk = blockIdx.x;
  const int bkh = blk & 31;          // b*8+kh  (same-kh blocks -> same XCD)
  const int tile = 63 - (blk >> 5);  // long tiles dispatch first
  const int b = bkh >> 3, kh = bkh & 7;
  const int tid = threadIdx.x;
  const int w = tid >> 6, lane = tid & 63, l15 = lane & 15, l4 = lane >> 4;
  const int h = kh * 2 + (w >> 1);
  const int t0w = tile * 32 + (w & 1) * 16;
  const int thi = tile * 32 + 31;

  __shared__ unsigned short KT[2][4096];  // [buf][64 rows][64 d] swizzled chunks
  __shared__ unsigned short VT[2][4096];  // [buf][64 d][64 s] swizzled chunks
  __shared__ unsigned short P[4][16 * 72];
  unsigned short* Pw = &P[w][0];

  // Q as B-frag: lane l15 = q-row t, k = l4*8+i over d
  const unsigned short* qbase = qkv + (size_t)(b * 2048 + t0w + l15) * 2048 + h * 64;
  bfrag q0 = *(const bfrag*)(qbase + l4 * 8);
  bfrag q1 = *(const bfrag*)(qbase + 32 + l4 * 8);

  float mrun = -1e30f, lsum = 0.f;
  f4 o[4];
#pragma unroll
  for (int d = 0; d < 4; d++) o[d] = (f4){0.f, 0.f, 0.f, 0.f};

  const unsigned short* vbase = vt + (size_t)(b * 8 + kh) * 64 * 2048;
  const float sc2 = 0.125f * 1.4426950408889634f;  // 1/sqrt(64) * log2(e)

  auto STAGE = [&](int buf, int s0) {
#pragma unroll
    for (int p = 0; p < 2; ++p) {
      int c = p * 256 + w * 64 + lane;
      int r = c >> 3, sl = (c & 7) ^ (r & 7);
      gload16(qkv + (size_t)(b * 2048 + s0 + r) * 2048 + 1024 + kh * 64 + sl * 8,
              &KT[buf][(p * 256 + w * 64) * 8]);
      gload16(vbase + (size_t)r * 2048 + s0 + sl * 8,
              &VT[buf][(p * 256 + w * 64) * 8]);
    }
  };

  STAGE(0, 0);
  int cur = 0;
  for (int s0 = 0; s0 <= thi; s0 += 64) {
    if (s0 + 64 <= thi) {
      STAGE(cur ^ 1, s0 + 64);
      asm volatile("s_waitcnt vmcnt(4)" ::: "memory");
    } else {
      asm volatile("s_waitcnt vmcnt(0)" ::: "memory");
    }
    __builtin_amdgcn_s_barrier();

    // ---- QK^T: 4 sub-tiles of 16 s ----
    f4 sa[4];
#pragma unroll
    for (int sub = 0; sub < 4; ++sub) {
      int rb = sub * 16 + l15;
      int x = rb & 7;
      bfrag k0 = *(const bfrag*)&KT[cur][(rb * 8 + (l4 ^ x)) * 8];
      bfrag k1 = *(const bfrag*)&KT[cur][(rb * 8 + ((l4 + 4) ^ x)) * 8];
      f4 z = (f4){0.f, 0.f, 0.f, 0.f};
      z = __builtin_amdgcn_mfma_f32_16x16x32_bf16(k0, q0, z, 0, 0, 0);
      z = __builtin_amdgcn_mfma_f32_16x16x32_bf16(k1, q1, z, 0, 0, 0);
      sa[sub] = z;
    }
    // ---- softmax (log2 domain), t = t0w + l15 ----
    const int t = t0w + l15;
    float pv[4][4];
    float mloc = -1e30f;
#pragma unroll
    for (int sub = 0; sub < 4; ++sub)
#pragma unroll
      for (int j = 0; j < 4; ++j) {
        int s = s0 + sub * 16 + l4 * 4 + j;
        float v = sa[sub][j] * sc2;
        if (s > t) v = -1e30f;
        pv[sub][j] = v;
        mloc = fmaxf(mloc, v);
      }
    mloc = fmaxf(mloc, __shfl_xor(mloc, 16));
    mloc = fmaxf(mloc, __shfl_xor(mloc, 32));
    float mnew = fmaxf(mrun, mloc);
    float al = __builtin_amdgcn_exp2f(mrun - mnew);
    mrun = mnew;
    float rs = 0.f;
#pragma unroll
    for (int sub = 0; sub < 4; ++sub)
#pragma unroll
      for (int j = 0; j < 4; ++j) {
        float e = __builtin_amdgcn_exp2f(pv[sub][j] - mnew);
        pv[sub][j] = e;
        rs += e;
      }
    rs += __shfl_xor(rs, 16);
    rs += __shfl_xor(rs, 32);
    lsum = lsum * al + rs;
#pragma unroll
    for (int d = 0; d < 4; d++)
#pragma unroll
      for (int j = 0; j < 4; j++) o[d][j] *= al;

    // ---- P -> bf16 -> per-wave LDS [16 t][64 s] (stride 72) ----
#pragma unroll
    for (int sub = 0; sub < 4; ++sub) {
      uint2 u;
      u.x = cvt_pk_bf16(pv[sub][0], pv[sub][1]);
      u.y = cvt_pk_bf16(pv[sub][2], pv[sub][3]);
      *(uint2*)&Pw[l15 * 72 + sub * 16 + l4 * 4] = u;
    }
    // ---- PV: O^T += Vt-frag @ P-frag ----
#pragma unroll
    for (int sh = 0; sh < 2; ++sh) {
      bfrag pf = *(const bfrag*)&Pw[l15 * 72 + sh * 32 + l4 * 8];
#pragma unroll
      for (int dblk = 0; dblk < 4; ++dblk) {
        int d = dblk * 16 + l15;
        bfrag vf = *(const bfrag*)&VT[cur][(d * 8 + ((sh * 4 + l4) ^ (d & 7))) * 8];
        o[dblk] = __builtin_amdgcn_mfma_f32_16x16x32_bf16(vf, pf, o[dblk], 0, 0, 0);
      }
    }
    asm volatile("s_waitcnt lgkmcnt(0)" ::: "memory");
    __builtin_amdgcn_s_barrier();
    cur ^= 1;
  }
  // o[dblk][j]: col t = l15, row d = dblk*16 + l4*4 + j
  float inv = 1.0f / lsum;
#pragma unroll
  for (int d = 0; d < 4; d++) {
    ushort4 st;
    st.x = f2bf(o[d][0] * inv);
    st.y = f2bf(o[d][1] * inv);
    st.z = f2bf(o[d][2] * inv);
    st.w = f2bf(o[d][3] * inv);
    *(ushort4*)&out[(size_t)(b * 2048 + t0w + l15) * 1024 + h * 64 + d * 16 + l4 * 4] = st;
  }
}

// ---------- launcher ----------
extern "C" void kernel_launch(void* const* d_in, const int* in_sizes, int n_in,
                              void* d_out, int out_size, void* d_ws, size_t ws_size,
                              hipStream_t stream) {
  const float* x = (const float*)d_in[0];
  const float* g1 = (const float*)d_in[1];
  const float* g2 = (const float*)d_in[2];
  const float* wq = (const float*)d_in[3];
  const float* wk = (const float*)d_in[4];
  const float* wv = (const float*)d_in[5];
  const float* wo = (const float*)d_in[6];
  const float* w1 = (const float*)d_in[7];
  const float* w2 = (const float*)d_in[8];
  const float* w3 = (const float*)d_in[9];

  const size_t MB = 1024 * 1024;
  uint8_t* ws = (uint8_t*)d_ws;
  unsigned short* wqkv_t = (unsigned short*)(ws);            // [2048][1024] bf16
  unsigned short* wo_t = (unsigned short*)(ws + 4 * MB);     // [1024][1024]
  unsigned short* w1_t = (unsigned short*)(ws + 6 * MB);     // [4096][1024]
  unsigned short* w2_t = (unsigned short*)(ws + 14 * MB);    // [4096][1024]
  unsigned short* w3_t = (unsigned short*)(ws + 22 * MB);    // [1024][4096]
  unsigned short* hbuf = (unsigned short*)(ws + 30 * MB);    // [8192][1024] h / h2
  unsigned short* qkv = (unsigned short*)(ws + 46 * MB);     // [8192][2048]
  unsigned short* vt = (unsigned short*)(ws + 78 * MB);      // [2048][2048]
  unsigned short* attn_o = (unsigned short*)(ws + 86 * MB);  // [8192][1024]
  unsigned short* gbuf = (unsigned short*)(ws + 46 * MB);    // [8192][4096] reuse qkv/vt/attn_o
  float* x1 = (float*)(ws + 110 * MB);                       // [8192][1024] fp32

  // weights -> bf16 transposed
  tconv_k<<<dim3(32, 32), 256, 0, stream>>>(wq, wqkv_t, 1024, 1024);
  tconv_k<<<dim3(16, 32), 256, 0, stream>>>(wk, wqkv_t + (size_t)1024 * 1024, 1024, 512);
  tconv_k<<<dim3(16, 32), 256, 0, stream>>>(wv, wqkv_t + (size_t)1536 * 1024, 1024, 512);
  tconv_k<<<dim3(32, 32), 256, 0, stream>>>(wo, wo_t, 1024, 1024);
  tconv_k<<<dim3(128, 32), 256, 0, stream>>>(w1, w1_t, 1024, 4096);
  tconv_k<<<dim3(128, 32), 256, 0, stream>>>(w2, w2_t, 1024, 4096);
  tconv_k<<<dim3(32, 128), 256, 0, stream>>>(w3, w3_t, 4096, 1024);

  rmsnorm_k<<<8192, 256, 0, stream>>>(x, g1, hbuf);
  gemm_k<0><<<dim3(64, 16), 256, 0, stream>>>(hbuf, wqkv_t, 8192, 2048, 1024, qkv, nullptr);
  rope_k<<<24576, 256, 0, stream>>>(qkv);
  vtrans_k<<<dim3(32, 32), 256, 0, stream>>>(qkv, vt);
  attn_k<<<2048, 256, 0, stream>>>(qkv, vt, attn_o);
  gemm_k<1><<<dim3(64, 8), 256, 0, stream>>>(attn_o, wo_t, 8192, 1024, 1024, x1, x);
  rmsnorm_k<<<8192, 256, 0, stream>>>(x1, g2, hbuf);
  ffn1_k<<<dim3(64, 64), 256, 0, stream>>>(hbuf, w1_t, w2_t, gbuf, 8192, 4096, 1024);
  gemm_k<1><<<dim3(64, 8), 256, 0, stream>>>(gbuf, w3_t, 8192, 1024, 4096, (float*)d_out, x1);
}

// Round 9
// 628.665 us; speedup vs baseline: 1.8084x; 1.0316x over previous
//
#include <hip/hip_runtime.h>
#include <cstdint>

// ---------- types / helpers ----------
typedef __attribute__((ext_vector_type(8))) short bfrag;   // 8 bf16 in 4 VGPRs
typedef __attribute__((ext_vector_type(4))) float f4;

typedef __attribute__((address_space(1))) const void* gas_t;
typedef __attribute__((address_space(3))) void* las_t;

__device__ __forceinline__ void gload16(const void* g, void* l) {
  __builtin_amdgcn_global_load_lds((gas_t)g, (las_t)l, 16, 0, 0);
}

__device__ __forceinline__ unsigned short f2bf(float f) {
  union { float f; unsigned u; } v; v.f = f;
  unsigned r = v.u + 0x7fffu + ((v.u >> 16) & 1u);
  return (unsigned short)(r >> 16);
}
__device__ __forceinline__ float bf2f(unsigned short b) {
  union { unsigned u; float f; } v; v.u = ((unsigned)b) << 16;
  return v.f;
}
__device__ __forceinline__ unsigned cvt_pk_bf16(float lo, float hi) {
  unsigned r;
  asm("v_cvt_pk_bf16_f32 %0, %1, %2" : "=v"(r) : "v"(lo), "v"(hi));
  return r;
}

// XCD-aware bijective block swizzle (nwg % 8 == 0 for all our grids)
__device__ __forceinline__ void xcd_swz(int& bx, int& by) {
  int gx = gridDim.x;
  int lid = blockIdx.y * gx + blockIdx.x;
  int nwg = gx * gridDim.y;
  int swz = (lid & 7) * (nwg >> 3) + (lid >> 3);
  bx = swz % gx;
  by = swz / gx;
}

// ---------- transpose+convert: in[R][C] fp32 -> out[C][R] bf16 ----------
__global__ __launch_bounds__(256) void tconv_k(const float* __restrict__ in,
                                               unsigned short* __restrict__ out,
                                               int R, int C) {
  __shared__ unsigned short t[32][33];
  const int c0 = blockIdx.x * 32, r0 = blockIdx.y * 32;
  const int tid = threadIdx.x;
#pragma unroll
  for (int p = 0; p < 4; p++) {
    int flat = p * 256 + tid;
    int r = flat >> 5, c = flat & 31;
    t[r][c] = f2bf(in[(size_t)(r0 + r) * C + c0 + c]);
  }
  __syncthreads();
#pragma unroll
  for (int p = 0; p < 4; p++) {
    int flat = p * 256 + tid;
    int cc = flat >> 5, rr = flat & 31;
    out[(size_t)(c0 + cc) * R + r0 + rr] = t[rr][cc];
  }
}

// ---------- RMSNorm: x fp32 [rows][1024] -> bf16 ----------
__global__ __launch_bounds__(256) void rmsnorm_k(const float* __restrict__ x,
                                                 const float* __restrict__ g,
                                                 unsigned short* __restrict__ out) {
  const int row = blockIdx.x, tid = threadIdx.x;
  const float4 v = ((const float4*)(x + (size_t)row * 1024))[tid];
  float ss = v.x * v.x + v.y * v.y + v.z * v.z + v.w * v.w;
#pragma unroll
  for (int off = 1; off < 64; off <<= 1) ss += __shfl_xor(ss, off);
  __shared__ float red[4];
  if ((tid & 63) == 0) red[tid >> 6] = ss;
  __syncthreads();
  float tot = red[0] + red[1] + red[2] + red[3];
  float sc = rsqrtf(tot * (1.0f / 1024.0f) + 1e-6f);
  const float4 gv = ((const float4*)g)[tid];
  ushort4 o;
  o.x = f2bf(v.x * sc * gv.x);
  o.y = f2bf(v.y * sc * gv.y);
  o.z = f2bf(v.z * sc * gv.z);
  o.w = f2bf(v.w * sc * gv.w);
  ((ushort4*)out)[(size_t)row * 256 + tid] = o;
}

// ---------- GEMM: C[M,N] = A[M,K](bf16) @ Bt[N,K](bf16)^T ----------
// 128x128 tile, XOR-swizzled LDS chunks, XCD swizzle.
// MODE 0: write bf16 C.  MODE 1: write fp32 C = acc + resid.
template <int MODE>
__global__ __launch_bounds__(256) void gemm_k(const unsigned short* __restrict__ A,
                                              const unsigned short* __restrict__ Bt,
                                              int M, int N, int K,
                                              void* __restrict__ Cout,
                                              const float* __restrict__ resid) {
  __shared__ unsigned short As[128 * 32];
  __shared__ unsigned short Bs[128 * 32];
  const int tid = threadIdx.x;
  const int wid = tid >> 6, lane = tid & 63;
  const int l15 = lane & 15, l4 = lane >> 4;
  int bx, by;
  xcd_swz(bx, by);
  const int brow = bx * 128, bcol = by * 128;
  const int wr = (wid >> 1) * 64, wc = (wid & 1) * 64;
  const int x15 = l15 & 3;  // row&3 for fragment rows
  f4 acc[4][4];
#pragma unroll
  for (int m = 0; m < 4; m++)
#pragma unroll
    for (int n = 0; n < 4; n++) acc[m][n] = (f4){0.f, 0.f, 0.f, 0.f};

  for (int k0 = 0; k0 < K; k0 += 32) {
#pragma unroll
    for (int c = 0; c < 2; c++) {
      int slot = c * 256 + tid;
      int r = slot >> 2, cp = slot & 3;
      int sc = (cp ^ (r & 3)) * 8;
      gload16(A + (size_t)(brow + r) * K + k0 + sc, &As[slot * 8]);
      gload16(Bt + (size_t)(bcol + r) * K + k0 + sc, &Bs[slot * 8]);
    }
    __syncthreads();
    bfrag a[4], b[4];
#pragma unroll
    for (int m = 0; m < 4; m++)
      a[m] = *(const bfrag*)&As[(wr + m * 16 + l15) * 32 + (l4 ^ x15) * 8];
#pragma unroll
    for (int n = 0; n < 4; n++)
      b[n] = *(const bfrag*)&Bs[(wc + n * 16 + l15) * 32 + (l4 ^ x15) * 8];
#pragma unroll
    for (int m = 0; m < 4; m++)
#pragma unroll
      for (int n = 0; n < 4; n++)
        acc[m][n] = __builtin_amdgcn_mfma_f32_16x16x32_bf16(a[m], b[n], acc[m][n], 0, 0, 0);
    __syncthreads();
  }
#pragma unroll
  for (int m = 0; m < 4; m++)
#pragma unroll
    for (int n = 0; n < 4; n++)
#pragma unroll
      for (int j = 0; j < 4; j++) {
        int r = brow + wr + m * 16 + l4 * 4 + j;
        int col = bcol + wc + n * 16 + l15;
        if (MODE == 0) {
          ((unsigned short*)Cout)[(size_t)r * N + col] = f2bf(acc[m][n][j]);
        } else {
          ((float*)Cout)[(size_t)r * N + col] = acc[m][n][j] + resid[(size_t)r * N + col];
        }
      }
}

// ---------- fused FFN1 (wave-split): G = silu(A@W1t^T) * (A@W2t^T) ----------
// 512 threads, 128x128 tile. Waves 0-3 compute P1, waves 4-7 compute P2 for
// the SAME tile (64-reg acc each). A staged once, shared. P2 -> LDS bf16
// exchange, waves 0-3 fuse + store.
__global__ __launch_bounds__(512) void ffn1_k(const unsigned short* __restrict__ A,
                                              const unsigned short* __restrict__ B1t,
                                              const unsigned short* __restrict__ B2t,
                                              unsigned short* __restrict__ G,
                                              int M, int N, int K) {
  __shared__ unsigned short LB[16640];  // union: stage 3*4096 | X 128*130
  unsigned short* As = LB;
  unsigned short* B1s = LB + 4096;
  unsigned short* B2s = LB + 8192;
  const int tid = threadIdx.x;
  const int w = tid >> 6, lane = tid & 63;
  const int l15 = lane & 15, l4 = lane >> 4;
  int bx, by;
  xcd_swz(bx, by);
  const int brow = bx * 128, bcol = by * 128;
  const int wq = w & 3;
  const int wr = (wq >> 1) * 64, wc = (wq & 1) * 64;
  const int x15 = l15 & 3;
  f4 acc[4][4];
#pragma unroll
  for (int m = 0; m < 4; m++)
#pragma unroll
    for (int n = 0; n < 4; n++) acc[m][n] = (f4){0.f, 0.f, 0.f, 0.f};

  for (int k0 = 0; k0 < K; k0 += 32) {
    {
      int r = tid >> 2, cp = tid & 3;
      int sc = (cp ^ (r & 3)) * 8;
      gload16(A + (size_t)(brow + r) * K + k0 + sc, &As[tid * 8]);
      gload16(B1t + (size_t)(bcol + r) * K + k0 + sc, &B1s[tid * 8]);
      gload16(B2t + (size_t)(bcol + r) * K + k0 + sc, &B2s[tid * 8]);
    }
    __syncthreads();
    const unsigned short* Bs = (w < 4) ? B1s : B2s;
    bfrag a[4], b[4];
#pragma unroll
    for (int m = 0; m < 4; m++)
      a[m] = *(const bfrag*)&As[(wr + m * 16 + l15) * 32 + (l4 ^ x15) * 8];
#pragma unroll
    for (int n = 0; n < 4; n++)
      b[n] = *(const bfrag*)&Bs[(wc + n * 16 + l15) * 32 + (l4 ^ x15) * 8];
#pragma unroll
    for (int m = 0; m < 4; m++)
#pragma unroll
      for (int n = 0; n < 4; n++)
        acc[m][n] = __builtin_amdgcn_mfma_f32_16x16x32_bf16(a[m], b[n], acc[m][n], 0, 0, 0);
    __syncthreads();
  }

  // exchange P2 via LDS (bf16, stride 130 to spread banks)
  if (w >= 4) {
#pragma unroll
    for (int m = 0; m < 4; m++)
#pragma unroll
      for (int n = 0; n < 4; n++)
#pragma unroll
        for (int j = 0; j < 4; j++)
          LB[(wr + m * 16 + l4 * 4 + j) * 130 + wc + n * 16 + l15] = f2bf(acc[m][n][j]);
  }
  __syncthreads();
  if (w < 4) {
#pragma unroll
    for (int m = 0; m < 4; m++)
#pragma unroll
      for (int n = 0; n < 4; n++)
#pragma unroll
        for (int j = 0; j < 4; j++) {
          int rr = wr + m * 16 + l4 * 4 + j;
          int cc = wc + n * 16 + l15;
          float v1 = acc[m][n][j];
          float v2 = bf2f(LB[rr * 130 + cc]);
          float sg = v1 / (1.0f + expf(-v1));
          G[(size_t)(brow + rr) * N + bcol + cc] = f2bf(sg * v2);
        }
  }
}

// ---------- RoPE in-place on q (16 heads) and k (8 heads) of qkv[8192][2048] ----------
__global__ __launch_bounds__(256) void rope_k(unsigned short* __restrict__ qkv) {
  int idx = blockIdx.x * 256 + threadIdx.x;  // 8192*24*32 total
  int i = idx & 31;
  int rest = idx >> 5;
  int head = rest % 24;
  int row = rest / 24;
  int t = row & 2047;
  int col = (head < 16) ? (head * 64 + i) : (1024 + (head - 16) * 64 + i);
  size_t base = (size_t)row * 2048 + col;
  float ang = (float)t * exp2f(-(float)i * (13.287712379549449f / 32.0f));
  float s, c;
  sincosf(ang, &s, &c);
  float a = bf2f(qkv[base]), b = bf2f(qkv[base + 32]);
  qkv[base] = f2bf(a * c - b * s);
  qkv[base + 32] = f2bf(b * c + a * s);
}

// ---------- V transpose: qkv v-cols -> vt[(b*8+kh)*64+d][T] ----------
__global__ __launch_bounds__(256) void vtrans_k(const unsigned short* __restrict__ qkv,
                                                unsigned short* __restrict__ vt) {
  __shared__ unsigned short t[64][65];
  const int t0 = blockIdx.x * 64;
  const int bkh = blockIdx.y;
  const int b = bkh >> 3, kh = bkh & 7;
  const int tid = threadIdx.x;
#pragma unroll
  for (int p = 0; p < 16; p++) {
    int flat = p * 256 + tid;
    int tl = flat >> 6, dl = flat & 63;
    t[tl][dl] = qkv[(size_t)(b * 2048 + t0 + tl) * 2048 + 1536 + kh * 64 + dl];
  }
  __syncthreads();
#pragma unroll
  for (int p = 0; p < 16; p++) {
    int flat = p * 256 + tid;
    int dl = flat >> 6, tl = flat & 63;
    vt[((size_t)(b * 8 + kh) * 64 + dl) * 2048 + t0 + tl] = t[tl][dl];
  }
}

// ---------- flash attention: LDS-staged KV, double-buffered, GQA-shared ----------
__global__ __launch_bounds__(256) void attn_k(const unsigned short* __restrict__ qkv,
                                              const unsigned short* __restrict__ vt,
                                              unsigned short* __restrict__ out) {
  const int blk = blockIdx.x;
  const int bkh = blk & 31;          // b*8+kh  (same-kh blocks -> same XCD)
  const int tile = 63 - (blk >> 5);  // long tiles dispatch first
  const int b = bkh >> 3, kh = bkh & 7;
  const int tid = threadIdx.x;
  const int w = tid >> 6, lane = tid & 63, l15 = lane & 15, l4 = lane >> 4;
  const int h = kh * 2 + (w >> 1);
  const int t0w = tile * 32 + (w & 1) * 16;
  const int thi = tile * 32 + 31;

  __shared__ unsigned short KT[2][4096];  // [buf][64 rows][64 d] swizzled chunks
  __shared__ unsigned short VT[2][4096];  // [buf][64 d][64 s] swizzled chunks
  __shared__ unsigned short P[4][16 * 72];
  unsigned short* Pw = &P[w][0];

  // Q as B-frag: lane l15 = q-row t, k = l4*8+i over d
  const unsigned short* qbase = qkv + (size_t)(b * 2048 + t0w + l15) * 2048 + h * 64;
  bfrag q0 = *(const bfrag*)(qbase + l4 * 8);
  bfrag q1 = *(const bfrag*)(qbase + 32 + l4 * 8);

  float mrun = -1e30f, lsum = 0.f;
  f4 o[4];
#pragma unroll
  for (int d = 0; d < 4; d++) o[d] = (f4){0.f, 0.f, 0.f, 0.f};

  const unsigned short* vbase = vt + (size_t)(b * 8 + kh) * 64 * 2048;
  const float sc2 = 0.125f * 1.4426950408889634f;  // 1/sqrt(64) * log2(e)

  auto STAGE = [&](int buf, int s0) {
#pragma unroll
    for (int p = 0; p < 2; ++p) {
      int c = p * 256 + w * 64 + lane;
      int r = c >> 3, sl = (c & 7) ^ (r & 7);
      gload16(qkv + (size_t)(b * 2048 + s0 + r) * 2048 + 1024 + kh * 64 + sl * 8,
              &KT[buf][(p * 256 + w * 64) * 8]);
      gload16(vbase + (size_t)r * 2048 + s0 + sl * 8,
              &VT[buf][(p * 256 + w * 64) * 8]);
    }
  };

  STAGE(0, 0);
  int cur = 0;
  for (int s0 = 0; s0 <= thi; s0 += 64) {
    if (s0 + 64 <= thi) {
      STAGE(cur ^ 1, s0 + 64);
      asm volatile("s_waitcnt vmcnt(4)" ::: "memory");
    } else {
      asm volatile("s_waitcnt vmcnt(0)" ::: "memory");
    }
    __builtin_amdgcn_s_barrier();

    // ---- QK^T: 4 sub-tiles of 16 s ----
    f4 sa[4];
#pragma unroll
    for (int sub = 0; sub < 4; ++sub) {
      int rb = sub * 16 + l15;
      int x = rb & 7;
      bfrag k0 = *(const bfrag*)&KT[cur][(rb * 8 + (l4 ^ x)) * 8];
      bfrag k1 = *(const bfrag*)&KT[cur][(rb * 8 + ((l4 + 4) ^ x)) * 8];
      f4 z = (f4){0.f, 0.f, 0.f, 0.f};
      z = __builtin_amdgcn_mfma_f32_16x16x32_bf16(k0, q0, z, 0, 0, 0);
      z = __builtin_amdgcn_mfma_f32_16x16x32_bf16(k1, q1, z, 0, 0, 0);
      sa[sub] = z;
    }
    // ---- softmax (log2 domain), t = t0w + l15 ----
    const int t = t0w + l15;
    float pv[4][4];
    float mloc = -1e30f;
#pragma unroll
    for (int sub = 0; sub < 4; ++sub)
#pragma unroll
      for (int j = 0; j < 4; ++j) {
        int s = s0 + sub * 16 + l4 * 4 + j;
        float v = sa[sub][j] * sc2;
        if (s > t) v = -1e30f;
        pv[sub][j] = v;
        mloc = fmaxf(mloc, v);
      }
    mloc = fmaxf(mloc, __shfl_xor(mloc, 16));
    mloc = fmaxf(mloc, __shfl_xor(mloc, 32));
    float mnew = fmaxf(mrun, mloc);
    float al = __builtin_amdgcn_exp2f(mrun - mnew);
    mrun = mnew;
    float rs = 0.f;
#pragma unroll
    for (int sub = 0; sub < 4; ++sub)
#pragma unroll
      for (int j = 0; j < 4; ++j) {
        float e = __builtin_amdgcn_exp2f(pv[sub][j] - mnew);
        pv[sub][j] = e;
        rs += e;
      }
    rs += __shfl_xor(rs, 16);
    rs += __shfl_xor(rs, 32);
    lsum = lsum * al + rs;
#pragma unroll
    for (int d = 0; d < 4; d++)
#pragma unroll
      for (int j = 0; j < 4; j++) o[d][j] *= al;

    // ---- P -> bf16 -> per-wave LDS [16 t][64 s] (stride 72) ----
#pragma unroll
    for (int sub = 0; sub < 4; ++sub) {
      uint2 u;
      u.x = cvt_pk_bf16(pv[sub][0], pv[sub][1]);
      u.y = cvt_pk_bf16(pv[sub][2], pv[sub][3]);
      *(uint2*)&Pw[l15 * 72 + sub * 16 + l4 * 4] = u;
    }
    // ---- PV: O^T += Vt-frag @ P-frag ----
#pragma unroll
    for (int sh = 0; sh < 2; ++sh) {
      bfrag pf = *(const bfrag*)&Pw[l15 * 72 + sh * 32 + l4 * 8];
#pragma unroll
      for (int dblk = 0; dblk < 4; ++dblk) {
        int d = dblk * 16 + l15;
        bfrag vf = *(const bfrag*)&VT[cur][(d * 8 + ((sh * 4 + l4) ^ (d & 7))) * 8];
        o[dblk] = __builtin_amdgcn_mfma_f32_16x16x32_bf16(vf, pf, o[dblk], 0, 0, 0);
      }
    }
    asm volatile("s_waitcnt lgkmcnt(0)" ::: "memory");
    __builtin_amdgcn_s_barrier();
    cur ^= 1;
  }
  // o[dblk][j]: col t = l15, row d = dblk*16 + l4*4 + j
  float inv = 1.0f / lsum;
#pragma unroll
  for (int d = 0; d < 4; d++) {
    ushort4 st;
    st.x = f2bf(o[d][0] * inv);
    st.y = f2bf(o[d][1] * inv);
    st.z = f2bf(o[d][2] * inv);
    st.w = f2bf(o[d][3] * inv);
    *(ushort4*)&out[(size_t)(b * 2048 + t0w + l15) * 1024 + h * 64 + d * 16 + l4 * 4] = st;
  }
}

// ---------- launcher ----------
extern "C" void kernel_launch(void* const* d_in, const int* in_sizes, int n_in,
                              void* d_out, int out_size, void* d_ws, size_t ws_size,
                              hipStream_t stream) {
  const float* x = (const float*)d_in[0];
  const float* g1 = (const float*)d_in[1];
  const float* g2 = (const float*)d_in[2];
  const float* wq = (const float*)d_in[3];
  const float* wk = (const float*)d_in[4];
  const float* wv = (const float*)d_in[5];
  const float* wo = (const float*)d_in[6];
  const float* w1 = (const float*)d_in[7];
  const float* w2 = (const float*)d_in[8];
  const float* w3 = (const float*)d_in[9];

  const size_t MB = 1024 * 1024;
  uint8_t* ws = (uint8_t*)d_ws;
  unsigned short* wqkv_t = (unsigned short*)(ws);            // [2048][1024] bf16
  unsigned short* wo_t = (unsigned short*)(ws + 4 * MB);     // [1024][1024]
  unsigned short* w1_t = (unsigned short*)(ws + 6 * MB);     // [4096][1024]
  unsigned short* w2_t = (unsigned short*)(ws + 14 * MB);    // [4096][1024]
  unsigned short* w3_t = (unsigned short*)(ws + 22 * MB);    // [1024][4096]
  unsigned short* hbuf = (unsigned short*)(ws + 30 * MB);    // [8192][1024] h / h2
  unsigned short* qkv = (unsigned short*)(ws + 46 * MB);     // [8192][2048]
  unsigned short* vt = (unsigned short*)(ws + 78 * MB);      // [2048][2048]
  unsigned short* attn_o = (unsigned short*)(ws + 86 * MB);  // [8192][1024]
  unsigned short* gbuf = (unsigned short*)(ws + 46 * MB);    // [8192][4096] reuse qkv/vt/attn_o
  float* x1 = (float*)(ws + 110 * MB);                       // [8192][1024] fp32

  // weights -> bf16 transposed
  tconv_k<<<dim3(32, 32), 256, 0, stream>>>(wq, wqkv_t, 1024, 1024);
  tconv_k<<<dim3(16, 32), 256, 0, stream>>>(wk, wqkv_t + (size_t)1024 * 1024, 1024, 512);
  tconv_k<<<dim3(16, 32), 256, 0, stream>>>(wv, wqkv_t + (size_t)1536 * 1024, 1024, 512);
  tconv_k<<<dim3(32, 32), 256, 0, stream>>>(wo, wo_t, 1024, 1024);
  tconv_k<<<dim3(128, 32), 256, 0, stream>>>(w1, w1_t, 1024, 4096);
  tconv_k<<<dim3(128, 32), 256, 0, stream>>>(w2, w2_t, 1024, 4096);
  tconv_k<<<dim3(32, 128), 256, 0, stream>>>(w3, w3_t, 4096, 1024);

  rmsnorm_k<<<8192, 256, 0, stream>>>(x, g1, hbuf);
  gemm_k<0><<<dim3(64, 16), 256, 0, stream>>>(hbuf, wqkv_t, 8192, 2048, 1024, qkv, nullptr);
  rope_k<<<24576, 256, 0, stream>>>(qkv);
  vtrans_k<<<dim3(32, 32), 256, 0, stream>>>(qkv, vt);
  attn_k<<<2048, 256, 0, stream>>>(qkv, vt, attn_o);
  gemm_k<1><<<dim3(64, 8), 256, 0, stream>>>(attn_o, wo_t, 8192, 1024, 1024, x1, x);
  rmsnorm_k<<<8192, 256, 0, stream>>>(x1, g2, hbuf);
  ffn1_k<<<dim3(64, 32), 512, 0, stream>>>(hbuf, w1_t, w2_t, gbuf, 8192, 4096, 1024);
  gemm_k<1><<<dim3(64, 8), 256, 0, stream>>>(gbuf, w3_t, 8192, 1024, 4096, (float*)d_out, x1);
}